// Round 5
// baseline (177.145 us; speedup 1.0000x reference)
//
#include <hip/hip_runtime.h>
#include <math.h>

#define DDIM 2048
#define NEXP 64
#define BM 32            // (mono fallback tile)
#define BK 64
#define TOKB 64          // tokens per block (main kernel)
#define CK 64            // k-chunk staged in LDS
#define EPW 16           // experts per wave
#define THETA 1e-5f
#define MAXFLAG 16383
#define FLAGREGION 65536
#define WTBYTES (DDIM * NEXP * 4)   // 512 KB transposed W

// ---------------------------------------------------------------------------
// Kernel 0: one-time W[64][2048] -> Wt[2048][64] transpose (512 KB).
// Thread g: k = g>>4, e-quad = (g&15)*4; scattered reads (L2-absorbed),
// fully-coalesced float4 writes.
// ---------------------------------------------------------------------------
__global__ void wt_transpose(const float* __restrict__ W, float* __restrict__ Wt) {
    const int gid = blockIdx.x * 256 + threadIdx.x;   // 0..32767
    const int k = gid >> 4;
    const int eq = (gid & 15) * 4;
    float4 v;
    v.x = W[(size_t)(eq + 0) * DDIM + k];
    v.y = W[(size_t)(eq + 1) * DDIM + k];
    v.z = W[(size_t)(eq + 2) * DDIM + k];
    v.w = W[(size_t)(eq + 3) * DDIM + k];
    *(float4*)(Wt + (size_t)k * NEXP + eq) = v;
}

// ---------------------------------------------------------------------------
// Kernel 1 (split-K, scalar-W scheme): P[s][t][e] partial logits.
// lane = token; wave wv owns experts [16wv,16wv+16). Per k:
//   - x_s[k][lane] via ds_read_b32 (stride-65 pad, conflict-free)
//   - Wt[k][16wv..+15] via wave-uniform load -> s_load_dwordx16 (SMEM pipe)
//   - 16 v_fmac (SGPR x VGPR) into 16 accs.
// Round-4 version staged W through LDS: 3 B/FMA -> 6.4 GB LDS traffic -> 93us
// LDS-bound. This cuts LDS to x-broadcast only (~0.5 GB).
// ---------------------------------------------------------------------------
__launch_bounds__(256)
__global__ void gate_main(const float* __restrict__ x, const float* __restrict__ Wt,
                          float* __restrict__ P, int M, int S) {
    __shared__ __align__(16) float xs[CK][TOKB + 1];   // stride 65: bank = (k+t)%32

    const int tid = threadIdx.x;
    const int lane = tid & 63;
    const int wvu = __builtin_amdgcn_readfirstlane(tid >> 6);  // provably uniform
    const int nblk = M / TOKB;               // 256
    const int tb = blockIdx.x % nblk;
    const int s = blockIdx.x / nblk;
    const int tok0 = tb * TOKB;
    const int KS = DDIM / S;
    const int k0 = s * KS;
    const int nch = KS / CK;

    // staging role: token si+16p (p=0..3), k-quad sq. Lanes: sq fastest ->
    // 16 lanes x 16 B = 256 B contiguous per token row.
    const int si = tid >> 4;                 // 0..15
    const int sq = tid & 15;                 // k offset 4*sq

    float acc[EPW];
#pragma unroll
    for (int j = 0; j < EPW; ++j) acc[j] = 0.f;

    const float* wbase = Wt + wvu * EPW;     // + k*NEXP, wave-uniform

    float4 st[4];
#pragma unroll
    for (int p = 0; p < 4; ++p)
        st[p] = *(const float4*)(x + (size_t)(tok0 + si + 16 * p) * DDIM + k0 + 4 * sq);

    for (int ch = 0; ch < nch; ++ch) {
        __syncthreads();
#pragma unroll
        for (int p = 0; p < 4; ++p) {        // transpose into LDS; 2-way max (free)
            xs[4 * sq + 0][si + 16 * p] = st[p].x;
            xs[4 * sq + 1][si + 16 * p] = st[p].y;
            xs[4 * sq + 2][si + 16 * p] = st[p].z;
            xs[4 * sq + 3][si + 16 * p] = st[p].w;
        }
        __syncthreads();
        if (ch + 1 < nch) {                  // prefetch next chunk (overlaps compute)
            const int kc = k0 + (ch + 1) * CK;
#pragma unroll
            for (int p = 0; p < 4; ++p)
                st[p] = *(const float4*)(x + (size_t)(tok0 + si + 16 * p) * DDIM + kc + 4 * sq);
        }
        const int kk0 = k0 + ch * CK;
#pragma unroll 8
        for (int k = 0; k < CK; ++k) {
            const float xv = xs[k][lane];
            const float4* wr = (const float4*)(wbase + (size_t)(kk0 + k) * NEXP);
#pragma unroll
            for (int j4 = 0; j4 < 4; ++j4) {
                const float4 w = wr[j4];
                acc[4 * j4 + 0] = fmaf(w.x, xv, acc[4 * j4 + 0]);
                acc[4 * j4 + 1] = fmaf(w.y, xv, acc[4 * j4 + 1]);
                acc[4 * j4 + 2] = fmaf(w.z, xv, acc[4 * j4 + 2]);
                acc[4 * j4 + 3] = fmaf(w.w, xv, acc[4 * j4 + 3]);
            }
        }
    }

    float* pb = P + (size_t)(s * M + tok0 + lane) * NEXP + wvu * EPW;
#pragma unroll
    for (int j4 = 0; j4 < 4; ++j4)
        *(float4*)(pb + 4 * j4) =
            make_float4(acc[4 * j4], acc[4 * j4 + 1], acc[4 * j4 + 2], acc[4 * j4 + 3]);
}

// ---------------------------------------------------------------------------
// Kernel 2: combine S partials -> sigmoid -> biased top-7 -> weights/indices.
// One wave per token, lane = expert; butterfly argmax (tie -> lower index).
// ---------------------------------------------------------------------------
__launch_bounds__(256)
__global__ void gate_combine(const float* __restrict__ P, const float* __restrict__ gb,
                             float* __restrict__ out, int* __restrict__ wsc,
                             int M, int S) {
    const int lane = threadIdx.x & 63;
    const int wv = threadIdx.x >> 6;
    const int t = blockIdx.x * 4 + wv;
    if (t >= M) return;

    float lgv = 0.f;
    for (int s = 0; s < S; ++s)
        lgv += P[(size_t)(s * M + t) * NEXP + lane];

    const float sg = 1.f / (1.f + expf(-lgv));
    float cur = sg + gb[lane];

    float vals[7]; int idxs[7]; float us[7];
#pragma unroll
    for (int p = 0; p < 7; ++p) {
        float v = cur; int id = lane;
#pragma unroll
        for (int o = 32; o > 0; o >>= 1) {
            const float ov = __shfl_xor(v, o, 64);
            const int oid = __shfl_xor(id, o, 64);
            const bool take = (ov > v) || (ov == v && oid < id);
            v = take ? ov : v;
            id = take ? oid : id;
        }
        vals[p] = v; idxs[p] = id;
        us[p] = __shfl(sg, id, 64);
        if (lane == id) cur = -1e30f;
    }

    if (lane == 0) {
        bool flag = false;
#pragma unroll
        for (int p = 0; p < 6; ++p) flag = flag || (vals[p] - vals[p + 1] < THETA);

        float sum = 0.f;
#pragma unroll
        for (int p = 0; p < 6; ++p) sum += us[p];
#pragma unroll
        for (int p = 0; p < 6; ++p)
            out[(size_t)t * 6 + p] = us[p] / sum * 2.5f;

        float* oi = out + (size_t)M * 6 + (size_t)t * 8;
        oi[0] = 0.f; oi[1] = 1.f;
#pragma unroll
        for (int p = 0; p < 6; ++p) oi[2 + p] = (float)(idxs[p] + 2);

        if (flag) {
            const int pos = atomicAdd(wsc, 1);
            if (pos < MAXFLAG) wsc[1 + pos] = t;
        }
    }
}

// ---------------------------------------------------------------------------
// Kernel 3: f64 refine of flagged tokens (exact ordering).
// ---------------------------------------------------------------------------
__launch_bounds__(256, 2)
__global__ void gate_refine(const float* __restrict__ x, const float* __restrict__ W,
                            const float* __restrict__ gb, float* __restrict__ out,
                            const int* __restrict__ wsc, int M) {
    __shared__ double lg[NEXP];
    int cnt = wsc[0];
    if (cnt > MAXFLAG) cnt = MAXFLAG;
    const int wv = threadIdx.x >> 6;
    const int lane = threadIdx.x & 63;

    for (int i = blockIdx.x; i < cnt; i += gridDim.x) {
        const int t = wsc[1 + i];
        const float* xr = x + (size_t)t * DDIM;
        for (int ee = 0; ee < 16; ++ee) {
            const int e = wv * 16 + ee;
            const float* wr = W + (size_t)e * DDIM;
            double a0 = 0, a1 = 0, a2 = 0, a3 = 0;
#pragma unroll
            for (int it = 0; it < DDIM / 256; ++it) {
                const float4 xv = *(const float4*)(xr + it * 256 + lane * 4);
                const float4 wvv = *(const float4*)(wr + it * 256 + lane * 4);
                a0 = fma((double)xv.x, (double)wvv.x, a0);
                a1 = fma((double)xv.y, (double)wvv.y, a1);
                a2 = fma((double)xv.z, (double)wvv.z, a2);
                a3 = fma((double)xv.w, (double)wvv.w, a3);
            }
            double sd = (a0 + a1) + (a2 + a3);
#pragma unroll
            for (int o = 32; o > 0; o >>= 1) sd += __shfl_down(sd, o, 64);
            if (lane == 0) lg[e] = sd;
        }
        __syncthreads();
        if (threadIdx.x < NEXP) {
            const double l = lg[threadIdx.x];
            lg[threadIdx.x] = 1.0 / (1.0 + exp(-l)) + (double)gb[threadIdx.x];
        }
        __syncthreads();
        if (threadIdx.x == 0) {
            double val[7]; int idx[7];
#pragma unroll
            for (int p = 0; p < 7; ++p) { val[p] = -1e30; idx[p] = 0; }
            for (int e = 0; e < NEXP; ++e) {
                double v = lg[e]; int id = e;
#pragma unroll
                for (int p = 0; p < 7; ++p) {
                    const bool gt = v > val[p];
                    const double ov = val[p]; const int oi2 = idx[p];
                    val[p] = gt ? v : ov; idx[p] = gt ? id : oi2;
                    v = gt ? ov : v;      id = gt ? oi2 : id;
                }
            }
            double s6[6], sum = 0.0;
#pragma unroll
            for (int p = 0; p < 6; ++p) { s6[p] = val[p] - (double)gb[idx[p]]; sum += s6[p]; }
#pragma unroll
            for (int p = 0; p < 6; ++p)
                out[(size_t)t * 6 + p] = (float)(s6[p] / sum * 2.5);
            float* oi = out + (size_t)M * 6 + (size_t)t * 8;
            oi[0] = 0.f; oi[1] = 1.f;
#pragma unroll
            for (int p = 0; p < 6; ++p) oi[2 + p] = (float)(idx[p] + 2);
        }
        __syncthreads();
    }
}

// ---------------------------------------------------------------------------
// Fallback: monolithic kernel (used only if ws too small for split-K + Wt)
// ---------------------------------------------------------------------------
__launch_bounds__(256, 2)
__global__ void gate_mono(const float* __restrict__ x, const float* __restrict__ W,
                          const float* __restrict__ gb, float* __restrict__ out,
                          int* __restrict__ wsc, int M) {
    __shared__ __align__(16) float xs[BK * BM];
    __shared__ __align__(16) float wsh[BK * NEXP];

    const int tid = threadIdx.x;
    const int tg = tid & 15;
    const int eg = tid >> 4;
    const int tok0 = blockIdx.x * BM;
    const int sr = tid >> 3;
    const int sq = tid & 7;
    const float* xsrc  = x + (size_t)(tok0 + sr) * DDIM + 4 * sq;
    const float* wsrc0 = W + (size_t)sr * DDIM + 4 * sq;
    const float* wsrc1 = W + (size_t)(sr + 32) * DDIM + 4 * sq;

    int xoff[16], woff[16];
#pragma unroll
    for (int c = 0; c < 16; ++c) {
        xoff[c] = c * (BM * 4) + 8 * (tg ^ c);
        woff[c] = c * (NEXP * 4) + 16 * (eg ^ c);
    }
    float acc[2][4];
#pragma unroll
    for (int i = 0; i < 2; ++i)
#pragma unroll
        for (int j = 0; j < 4; ++j) acc[i][j] = 0.f;

    float4 px0 = *(const float4*)(xsrc);
    float4 px1 = *(const float4*)(xsrc + 32);
    float4 pw00 = *(const float4*)(wsrc0);
    float4 pw01 = *(const float4*)(wsrc0 + 32);
    float4 pw10 = *(const float4*)(wsrc1);
    float4 pw11 = *(const float4*)(wsrc1 + 32);

    for (int ch = 0; ch < DDIM / BK; ++ch) {
        __syncthreads();
#pragma unroll
        for (int m = 0; m < 4; ++m) {
            const int kkA = 4 * sq + m;
            const int kkB = kkA + 32;
            xs[kkA * BM + ((sr & 1) + 2 * ((sr >> 1) ^ (kkA & 15)))] = ((const float*)&px0)[m];
            xs[kkB * BM + ((sr & 1) + 2 * ((sr >> 1) ^ (kkB & 15)))] = ((const float*)&px1)[m];
            wsh[kkA * NEXP + ((sr & 3) + 4 * ((sr >> 2) ^ (kkA & 15)))] = ((const float*)&pw00)[m];
            wsh[kkB * NEXP + ((sr & 3) + 4 * ((sr >> 2) ^ (kkB & 15)))] = ((const float*)&pw01)[m];
            wsh[kkA * NEXP + (((sr + 32) & 3) + 4 * (((sr + 32) >> 2) ^ (kkA & 15)))] = ((const float*)&pw10)[m];
            wsh[kkB * NEXP + (((sr + 32) & 3) + 4 * (((sr + 32) >> 2) ^ (kkB & 15)))] = ((const float*)&pw11)[m];
        }
        __syncthreads();
        if (ch + 1 < DDIM / BK) {
            const int k0 = (ch + 1) * BK;
            px0 = *(const float4*)(xsrc + k0);
            px1 = *(const float4*)(xsrc + k0 + 32);
            pw00 = *(const float4*)(wsrc0 + k0);
            pw01 = *(const float4*)(wsrc0 + k0 + 32);
            pw10 = *(const float4*)(wsrc1 + k0);
            pw11 = *(const float4*)(wsrc1 + k0 + 32);
        }
        const char* xb = (const char*)xs;
        const char* wb = (const char*)wsh;
#pragma unroll
        for (int rep = 0; rep < 4; ++rep) {
#pragma unroll
            for (int c = 0; c < 16; ++c) {
                const float2 xv = *(const float2*)(xb + rep * (16 * BM * 4) + xoff[c]);
                const float4 wv = *(const float4*)(wb + rep * (16 * NEXP * 4) + woff[c]);
                acc[0][0] = fmaf(xv.x, wv.x, acc[0][0]);
                acc[0][1] = fmaf(xv.x, wv.y, acc[0][1]);
                acc[0][2] = fmaf(xv.x, wv.z, acc[0][2]);
                acc[0][3] = fmaf(xv.x, wv.w, acc[0][3]);
                acc[1][0] = fmaf(xv.y, wv.x, acc[1][0]);
                acc[1][1] = fmaf(xv.y, wv.y, acc[1][1]);
                acc[1][2] = fmaf(xv.y, wv.z, acc[1][2]);
                acc[1][3] = fmaf(xv.y, wv.w, acc[1][3]);
            }
        }
    }

    __syncthreads();
    float* sc = wsh;
#pragma unroll
    for (int i = 0; i < 2; ++i)
#pragma unroll
        for (int j = 0; j < 4; ++j)
            sc[(2 * tg + i) * 68 + (4 * eg + j)] = acc[i][j];
    __syncthreads();

    if (tid < BM) {
        const int t = tok0 + tid;
        float val[7]; int idx[7];
#pragma unroll
        for (int p = 0; p < 7; ++p) { val[p] = -1e30f; idx[p] = 0; }
        for (int e = 0; e < NEXP; ++e) {
            const float l = sc[tid * 68 + e];
            const float sg = 1.f / (1.f + expf(-l));
            float v = sg + gb[e];
            int id = e;
#pragma unroll
            for (int p = 0; p < 7; ++p) {
                const bool gt = v > val[p];
                const float ov = val[p]; const int oi = idx[p];
                val[p] = gt ? v : ov;  idx[p] = gt ? id : oi;
                v = gt ? ov : v;       id = gt ? oi : id;
            }
        }
        bool flag = false;
#pragma unroll
        for (int p = 0; p < 6; ++p) flag = flag || (val[p] - val[p + 1] < THETA);

        float s6[6]; float sum = 0.f;
#pragma unroll
        for (int p = 0; p < 6; ++p) {
            const float l = sc[tid * 68 + idx[p]];
            s6[p] = 1.f / (1.f + expf(-l));
            sum += s6[p];
        }
#pragma unroll
        for (int p = 0; p < 6; ++p)
            out[(size_t)t * 6 + p] = s6[p] / sum * 2.5f;

        float* oi = out + (size_t)M * 6 + (size_t)t * 8;
        oi[0] = 0.f; oi[1] = 1.f;
#pragma unroll
        for (int p = 0; p < 6; ++p) oi[2 + p] = (float)(idx[p] + 2);

        if (flag && wsc) {
            const int pos = atomicAdd(wsc, 1);
            if (pos < MAXFLAG) wsc[1 + pos] = t;
        }
    }
}

extern "C" void kernel_launch(void* const* d_in, const int* in_sizes, int n_in,
                              void* d_out, int out_size, void* d_ws, size_t ws_size,
                              hipStream_t stream) {
    const float* x = (const float*)d_in[0];
    const float* W = (const float*)d_in[1];
    const float* gb = (const float*)d_in[2];
    float* out = (float*)d_out;
    const int M = in_sizes[0] / DDIM;   // 16384

    // ws layout: [flags 64KB | Wt 512KB | P S*M*64*4]
    int S = 0;
    for (int cand = 4; cand >= 1; cand >>= 1) {
        const size_t need = (size_t)FLAGREGION + WTBYTES +
                            (size_t)cand * M * NEXP * sizeof(float);
        if (ws_size >= need) { S = cand; break; }
    }

    if (S > 0) {
        int* wsc = (int*)d_ws;
        float* Wt = (float*)((char*)d_ws + FLAGREGION);
        float* P = (float*)((char*)d_ws + FLAGREGION + WTBYTES);
        hipMemsetAsync(d_ws, 0, sizeof(int), stream);
        hipLaunchKernelGGL(wt_transpose, dim3(DDIM * EPW / 256), dim3(256), 0, stream,
                           W, Wt);
        hipLaunchKernelGGL(gate_main, dim3((M / TOKB) * S), dim3(256), 0, stream,
                           x, Wt, P, M, S);
        hipLaunchKernelGGL(gate_combine, dim3((M + 3) / 4), dim3(256), 0, stream,
                           P, gb, out, wsc, M, S);
        hipLaunchKernelGGL(gate_refine, dim3(256), dim3(256), 0, stream,
                           x, W, gb, out, wsc, M);
    } else {
        const bool refine_ok = ws_size >= (size_t)(1 + MAXFLAG) * sizeof(int);
        int* wsc = refine_ok ? (int*)d_ws : (int*)nullptr;
        if (refine_ok) hipMemsetAsync(d_ws, 0, sizeof(int), stream);
        hipLaunchKernelGGL(gate_mono, dim3(M / BM), dim3(256), 0, stream,
                           x, W, gb, out, wsc, M);
        if (refine_ok)
            hipLaunchKernelGGL(gate_refine, dim3(256), dim3(256), 0, stream,
                               x, W, gb, out, wsc, M);
    }
}

// Round 6
// 150.186 us; speedup vs baseline: 1.1795x; 1.1795x over previous
//
#include <hip/hip_runtime.h>
#include <math.h>

#define DDIM 2048
#define NEXP 64
#define BM 32            // (mono fallback tile)
#define BK 64
#define TOKB 128         // tokens per block (main kernel): lane owns L, L+64
#define CK 32            // k-chunk staged in LDS
#define EPW 16           // experts per wave
#define THETA 1e-5f
#define MAXFLAG 16383
#define FLAGREGION 65536
#define WTBYTES (DDIM * NEXP * 4)   // 512 KB transposed W

// ---------------------------------------------------------------------------
// Kernel 0: one-time W[64][2048] -> Wt[2048][64] transpose (512 KB).
// ---------------------------------------------------------------------------
__global__ void wt_transpose(const float* __restrict__ W, float* __restrict__ Wt) {
    const int gid = blockIdx.x * 256 + threadIdx.x;   // 0..32767
    const int k = gid >> 4;
    const int eq = (gid & 15) * 4;
    float4 v;
    v.x = W[(size_t)(eq + 0) * DDIM + k];
    v.y = W[(size_t)(eq + 1) * DDIM + k];
    v.z = W[(size_t)(eq + 2) * DDIM + k];
    v.w = W[(size_t)(eq + 3) * DDIM + k];
    *(float4*)(Wt + (size_t)k * NEXP + eq) = v;
}

// ---------------------------------------------------------------------------
// Kernel 1 (split-K): P[s][t][e] partial logits.
// lane = token (owns tokens L and L+64); wave wv owns experts [16wv,16wv+16).
// W chunk staged in LDS; per-k W read = 4x ds_read_b128 at WAVE-UNIFORM addr
// (broadcast, conflict-free) -> pipelines under lgkmcnt with no SGPR ceiling.
// Round-5 version used s_load_dwordx16 for W: only ~2 loads in flight at 64
// SGPRs -> 75% SMEM-latency stall (VALUBusy 24% = exactly the FMA floor).
// ---------------------------------------------------------------------------
__launch_bounds__(256)
__global__ void gate_main(const float* __restrict__ x, const float* __restrict__ Wt,
                          float* __restrict__ P, int M, int S) {
    __shared__ __align__(16) float xs[CK][TOKB + 2];   // stride 130: 2-way max (free)
    __shared__ __align__(16) float wls[CK][NEXP];      // k-major W chunk (8 KB)

    const int tid = threadIdx.x;
    const int lane = tid & 63;
    const int wvu = __builtin_amdgcn_readfirstlane(tid >> 6);
    const int nblk = M / TOKB;               // 128
    const int tb = blockIdx.x % nblk;
    const int s = blockIdx.x / nblk;
    const int tok0 = tb * TOKB;
    const int KS = DDIM / S;
    const int k0 = s * KS;
    const int nch = KS / CK;

    // x staging role: 4 passes; token row str+32p, k-quad ssq (8 thr x 16B = 128B runs)
    const int str = tid >> 3;                // 0..31
    const int ssq = tid & 7;                 // k offset 4*ssq

    float acc[2][EPW];
#pragma unroll
    for (int i = 0; i < 2; ++i)
#pragma unroll
        for (int j = 0; j < EPW; ++j) acc[i][j] = 0.f;

    const float* xb = x + (size_t)(tok0 + str) * DDIM + k0 + 4 * ssq;
    const float* wtb = Wt + (size_t)k0 * NEXP;

    // prefetch chunk 0 into registers
    float4 xst[4], wst[2];
#pragma unroll
    for (int p = 0; p < 4; ++p)
        xst[p] = *(const float4*)(xb + (size_t)(32 * p) * DDIM);
#pragma unroll
    for (int q = 0; q < 2; ++q)
        wst[q] = *(const float4*)(wtb + q * 1024 + tid * 4);

    for (int ch = 0; ch < nch; ++ch) {
        __syncthreads();   // previous chunk's LDS reads finished
        // ---- store staged regs to LDS ----
#pragma unroll
        for (int p = 0; p < 4; ++p) {        // x transpose: 2-way bank alias max
            xs[4 * ssq + 0][str + 32 * p] = xst[p].x;
            xs[4 * ssq + 1][str + 32 * p] = xst[p].y;
            xs[4 * ssq + 2][str + 32 * p] = xst[p].z;
            xs[4 * ssq + 3][str + 32 * p] = xst[p].w;
        }
#pragma unroll
        for (int q = 0; q < 2; ++q)          // W: linear float4 copy
            *(float4*)((float*)wls + q * 1024 + tid * 4) = wst[q];
        __syncthreads();
        // ---- prefetch next chunk (overlaps compute) ----
        if (ch + 1 < nch) {
            const int kc = (ch + 1) * CK;
#pragma unroll
            for (int p = 0; p < 4; ++p)
                xst[p] = *(const float4*)(xb + (size_t)(32 * p) * DDIM + kc);
#pragma unroll
            for (int q = 0; q < 2; ++q)
                wst[q] = *(const float4*)(wtb + (size_t)kc * NEXP + q * 1024 + tid * 4);
        }
        // ---- compute: per k = 2 b32 (x, per-lane) + 4 b128 (W, broadcast) + 32 FMA ----
        const float* wr0 = &wls[0][EPW * wvu];
#pragma unroll 8
        for (int k = 0; k < CK; ++k) {
            const float xv0 = xs[k][lane];
            const float xv1 = xs[k][64 + lane];
            const float* wr = wr0 + k * NEXP;
#pragma unroll
            for (int j4 = 0; j4 < 4; ++j4) {
                const float4 w = *(const float4*)(wr + 4 * j4);
                acc[0][4 * j4 + 0] = fmaf(w.x, xv0, acc[0][4 * j4 + 0]);
                acc[0][4 * j4 + 1] = fmaf(w.y, xv0, acc[0][4 * j4 + 1]);
                acc[0][4 * j4 + 2] = fmaf(w.z, xv0, acc[0][4 * j4 + 2]);
                acc[0][4 * j4 + 3] = fmaf(w.w, xv0, acc[0][4 * j4 + 3]);
                acc[1][4 * j4 + 0] = fmaf(w.x, xv1, acc[1][4 * j4 + 0]);
                acc[1][4 * j4 + 1] = fmaf(w.y, xv1, acc[1][4 * j4 + 1]);
                acc[1][4 * j4 + 2] = fmaf(w.z, xv1, acc[1][4 * j4 + 2]);
                acc[1][4 * j4 + 3] = fmaf(w.w, xv1, acc[1][4 * j4 + 3]);
            }
        }
    }

    // write partial logits: token rows lane and lane+64 (both coalesced groups)
    float* pb0 = P + (size_t)(s * M + tok0 + lane) * NEXP + wvu * EPW;
    float* pb1 = pb0 + (size_t)64 * NEXP;
#pragma unroll
    for (int j4 = 0; j4 < 4; ++j4) {
        *(float4*)(pb0 + 4 * j4) = make_float4(acc[0][4 * j4], acc[0][4 * j4 + 1],
                                               acc[0][4 * j4 + 2], acc[0][4 * j4 + 3]);
        *(float4*)(pb1 + 4 * j4) = make_float4(acc[1][4 * j4], acc[1][4 * j4 + 1],
                                               acc[1][4 * j4 + 2], acc[1][4 * j4 + 3]);
    }
}

// ---------------------------------------------------------------------------
// Kernel 2: combine S partials -> sigmoid -> biased top-7 -> weights/indices.
// One wave per token, lane = expert; butterfly argmax (tie -> lower index).
// ---------------------------------------------------------------------------
__launch_bounds__(256)
__global__ void gate_combine(const float* __restrict__ P, const float* __restrict__ gb,
                             float* __restrict__ out, int* __restrict__ wsc,
                             int M, int S) {
    const int lane = threadIdx.x & 63;
    const int wv = threadIdx.x >> 6;
    const int t = blockIdx.x * 4 + wv;
    if (t >= M) return;

    float lgv = 0.f;
    for (int s = 0; s < S; ++s)
        lgv += P[(size_t)(s * M + t) * NEXP + lane];

    const float sg = 1.f / (1.f + expf(-lgv));
    float cur = sg + gb[lane];

    float vals[7]; int idxs[7]; float us[7];
#pragma unroll
    for (int p = 0; p < 7; ++p) {
        float v = cur; int id = lane;
#pragma unroll
        for (int o = 32; o > 0; o >>= 1) {
            const float ov = __shfl_xor(v, o, 64);
            const int oid = __shfl_xor(id, o, 64);
            const bool take = (ov > v) || (ov == v && oid < id);
            v = take ? ov : v;
            id = take ? oid : id;
        }
        vals[p] = v; idxs[p] = id;
        us[p] = __shfl(sg, id, 64);
        if (lane == id) cur = -1e30f;
    }

    if (lane == 0) {
        bool flag = false;
#pragma unroll
        for (int p = 0; p < 6; ++p) flag = flag || (vals[p] - vals[p + 1] < THETA);

        float sum = 0.f;
#pragma unroll
        for (int p = 0; p < 6; ++p) sum += us[p];
#pragma unroll
        for (int p = 0; p < 6; ++p)
            out[(size_t)t * 6 + p] = us[p] / sum * 2.5f;

        float* oi = out + (size_t)M * 6 + (size_t)t * 8;
        oi[0] = 0.f; oi[1] = 1.f;
#pragma unroll
        for (int p = 0; p < 6; ++p) oi[2 + p] = (float)(idxs[p] + 2);

        if (flag) {
            const int pos = atomicAdd(wsc, 1);
            if (pos < MAXFLAG) wsc[1 + pos] = t;
        }
    }
}

// ---------------------------------------------------------------------------
// Kernel 3: f64 refine of flagged tokens (exact ordering).
// ---------------------------------------------------------------------------
__launch_bounds__(256, 2)
__global__ void gate_refine(const float* __restrict__ x, const float* __restrict__ W,
                            const float* __restrict__ gb, float* __restrict__ out,
                            const int* __restrict__ wsc, int M) {
    __shared__ double lg[NEXP];
    int cnt = wsc[0];
    if (cnt > MAXFLAG) cnt = MAXFLAG;
    const int wv = threadIdx.x >> 6;
    const int lane = threadIdx.x & 63;

    for (int i = blockIdx.x; i < cnt; i += gridDim.x) {
        const int t = wsc[1 + i];
        const float* xr = x + (size_t)t * DDIM;
        for (int ee = 0; ee < 16; ++ee) {
            const int e = wv * 16 + ee;
            const float* wr = W + (size_t)e * DDIM;
            double a0 = 0, a1 = 0, a2 = 0, a3 = 0;
#pragma unroll
            for (int it = 0; it < DDIM / 256; ++it) {
                const float4 xv = *(const float4*)(xr + it * 256 + lane * 4);
                const float4 wvv = *(const float4*)(wr + it * 256 + lane * 4);
                a0 = fma((double)xv.x, (double)wvv.x, a0);
                a1 = fma((double)xv.y, (double)wvv.y, a1);
                a2 = fma((double)xv.z, (double)wvv.z, a2);
                a3 = fma((double)xv.w, (double)wvv.w, a3);
            }
            double sd = (a0 + a1) + (a2 + a3);
#pragma unroll
            for (int o = 32; o > 0; o >>= 1) sd += __shfl_down(sd, o, 64);
            if (lane == 0) lg[e] = sd;
        }
        __syncthreads();
        if (threadIdx.x < NEXP) {
            const double l = lg[threadIdx.x];
            lg[threadIdx.x] = 1.0 / (1.0 + exp(-l)) + (double)gb[threadIdx.x];
        }
        __syncthreads();
        if (threadIdx.x == 0) {
            double val[7]; int idx[7];
#pragma unroll
            for (int p = 0; p < 7; ++p) { val[p] = -1e30; idx[p] = 0; }
            for (int e = 0; e < NEXP; ++e) {
                double v = lg[e]; int id = e;
#pragma unroll
                for (int p = 0; p < 7; ++p) {
                    const bool gt = v > val[p];
                    const double ov = val[p]; const int oi2 = idx[p];
                    val[p] = gt ? v : ov; idx[p] = gt ? id : oi2;
                    v = gt ? ov : v;      id = gt ? oi2 : id;
                }
            }
            double s6[6], sum = 0.0;
#pragma unroll
            for (int p = 0; p < 6; ++p) { s6[p] = val[p] - (double)gb[idx[p]]; sum += s6[p]; }
#pragma unroll
            for (int p = 0; p < 6; ++p)
                out[(size_t)t * 6 + p] = (float)(s6[p] / sum * 2.5);
            float* oi = out + (size_t)M * 6 + (size_t)t * 8;
            oi[0] = 0.f; oi[1] = 1.f;
#pragma unroll
            for (int p = 0; p < 6; ++p) oi[2 + p] = (float)(idx[p] + 2);
        }
        __syncthreads();
    }
}

// ---------------------------------------------------------------------------
// Fallback: monolithic kernel (used only if ws too small for split-K + Wt)
// ---------------------------------------------------------------------------
__launch_bounds__(256, 2)
__global__ void gate_mono(const float* __restrict__ x, const float* __restrict__ W,
                          const float* __restrict__ gb, float* __restrict__ out,
                          int* __restrict__ wsc, int M) {
    __shared__ __align__(16) float xs[BK * BM];
    __shared__ __align__(16) float wsh[BK * NEXP];

    const int tid = threadIdx.x;
    const int tg = tid & 15;
    const int eg = tid >> 4;
    const int tok0 = blockIdx.x * BM;
    const int sr = tid >> 3;
    const int sq = tid & 7;
    const float* xsrc  = x + (size_t)(tok0 + sr) * DDIM + 4 * sq;
    const float* wsrc0 = W + (size_t)sr * DDIM + 4 * sq;
    const float* wsrc1 = W + (size_t)(sr + 32) * DDIM + 4 * sq;

    int xoff[16], woff[16];
#pragma unroll
    for (int c = 0; c < 16; ++c) {
        xoff[c] = c * (BM * 4) + 8 * (tg ^ c);
        woff[c] = c * (NEXP * 4) + 16 * (eg ^ c);
    }
    float acc[2][4];
#pragma unroll
    for (int i = 0; i < 2; ++i)
#pragma unroll
        for (int j = 0; j < 4; ++j) acc[i][j] = 0.f;

    float4 px0 = *(const float4*)(xsrc);
    float4 px1 = *(const float4*)(xsrc + 32);
    float4 pw00 = *(const float4*)(wsrc0);
    float4 pw01 = *(const float4*)(wsrc0 + 32);
    float4 pw10 = *(const float4*)(wsrc1);
    float4 pw11 = *(const float4*)(wsrc1 + 32);

    for (int ch = 0; ch < DDIM / BK; ++ch) {
        __syncthreads();
#pragma unroll
        for (int m = 0; m < 4; ++m) {
            const int kkA = 4 * sq + m;
            const int kkB = kkA + 32;
            xs[kkA * BM + ((sr & 1) + 2 * ((sr >> 1) ^ (kkA & 15)))] = ((const float*)&px0)[m];
            xs[kkB * BM + ((sr & 1) + 2 * ((sr >> 1) ^ (kkB & 15)))] = ((const float*)&px1)[m];
            wsh[kkA * NEXP + ((sr & 3) + 4 * ((sr >> 2) ^ (kkA & 15)))] = ((const float*)&pw00)[m];
            wsh[kkB * NEXP + ((sr & 3) + 4 * ((sr >> 2) ^ (kkB & 15)))] = ((const float*)&pw01)[m];
            wsh[kkA * NEXP + (((sr + 32) & 3) + 4 * (((sr + 32) >> 2) ^ (kkA & 15)))] = ((const float*)&pw10)[m];
            wsh[kkB * NEXP + (((sr + 32) & 3) + 4 * (((sr + 32) >> 2) ^ (kkB & 15)))] = ((const float*)&pw11)[m];
        }
        __syncthreads();
        if (ch + 1 < DDIM / BK) {
            const int k0 = (ch + 1) * BK;
            px0 = *(const float4*)(xsrc + k0);
            px1 = *(const float4*)(xsrc + k0 + 32);
            pw00 = *(const float4*)(wsrc0 + k0);
            pw01 = *(const float4*)(wsrc0 + k0 + 32);
            pw10 = *(const float4*)(wsrc1 + k0);
            pw11 = *(const float4*)(wsrc1 + k0 + 32);
        }
        const char* xb = (const char*)xs;
        const char* wb = (const char*)wsh;
#pragma unroll
        for (int rep = 0; rep < 4; ++rep) {
#pragma unroll
            for (int c = 0; c < 16; ++c) {
                const float2 xv = *(const float2*)(xb + rep * (16 * BM * 4) + xoff[c]);
                const float4 wv = *(const float4*)(wb + rep * (16 * NEXP * 4) + woff[c]);
                acc[0][0] = fmaf(xv.x, wv.x, acc[0][0]);
                acc[0][1] = fmaf(xv.x, wv.y, acc[0][1]);
                acc[0][2] = fmaf(xv.x, wv.z, acc[0][2]);
                acc[0][3] = fmaf(xv.x, wv.w, acc[0][3]);
                acc[1][0] = fmaf(xv.y, wv.x, acc[1][0]);
                acc[1][1] = fmaf(xv.y, wv.y, acc[1][1]);
                acc[1][2] = fmaf(xv.y, wv.z, acc[1][2]);
                acc[1][3] = fmaf(xv.y, wv.w, acc[1][3]);
            }
        }
    }

    __syncthreads();
    float* sc = wsh;
#pragma unroll
    for (int i = 0; i < 2; ++i)
#pragma unroll
        for (int j = 0; j < 4; ++j)
            sc[(2 * tg + i) * 68 + (4 * eg + j)] = acc[i][j];
    __syncthreads();

    if (tid < BM) {
        const int t = tok0 + tid;
        float val[7]; int idx[7];
#pragma unroll
        for (int p = 0; p < 7; ++p) { val[p] = -1e30f; idx[p] = 0; }
        for (int e = 0; e < NEXP; ++e) {
            const float l = sc[tid * 68 + e];
            const float sg = 1.f / (1.f + expf(-l));
            float v = sg + gb[e];
            int id = e;
#pragma unroll
            for (int p = 0; p < 7; ++p) {
                const bool gt = v > val[p];
                const float ov = val[p]; const int oi = idx[p];
                val[p] = gt ? v : ov;  idx[p] = gt ? id : oi;
                v = gt ? ov : v;       id = gt ? oi : id;
            }
        }
        bool flag = false;
#pragma unroll
        for (int p = 0; p < 6; ++p) flag = flag || (val[p] - val[p + 1] < THETA);

        float s6[6]; float sum = 0.f;
#pragma unroll
        for (int p = 0; p < 6; ++p) {
            const float l = sc[tid * 68 + idx[p]];
            s6[p] = 1.f / (1.f + expf(-l));
            sum += s6[p];
        }
#pragma unroll
        for (int p = 0; p < 6; ++p)
            out[(size_t)t * 6 + p] = s6[p] / sum * 2.5f;

        float* oi = out + (size_t)M * 6 + (size_t)t * 8;
        oi[0] = 0.f; oi[1] = 1.f;
#pragma unroll
        for (int p = 0; p < 6; ++p) oi[2 + p] = (float)(idx[p] + 2);

        if (flag && wsc) {
            const int pos = atomicAdd(wsc, 1);
            if (pos < MAXFLAG) wsc[1 + pos] = t;
        }
    }
}

extern "C" void kernel_launch(void* const* d_in, const int* in_sizes, int n_in,
                              void* d_out, int out_size, void* d_ws, size_t ws_size,
                              hipStream_t stream) {
    const float* x = (const float*)d_in[0];
    const float* W = (const float*)d_in[1];
    const float* gb = (const float*)d_in[2];
    float* out = (float*)d_out;
    const int M = in_sizes[0] / DDIM;   // 16384

    // ws layout: [flags 64KB | Wt 512KB | P S*M*64*4]
    int S = 0;
    for (int cand = 8; cand >= 2; cand >>= 1) {
        const size_t need = (size_t)FLAGREGION + WTBYTES +
                            (size_t)cand * M * NEXP * sizeof(float);
        if (ws_size >= need) { S = cand; break; }
    }

    if (S > 0) {
        int* wsc = (int*)d_ws;
        float* Wt = (float*)((char*)d_ws + FLAGREGION);
        float* P = (float*)((char*)d_ws + FLAGREGION + WTBYTES);
        hipMemsetAsync(d_ws, 0, sizeof(int), stream);
        hipLaunchKernelGGL(wt_transpose, dim3(DDIM * 16 / 256), dim3(256), 0, stream,
                           W, Wt);
        hipLaunchKernelGGL(gate_main, dim3((M / TOKB) * S), dim3(256), 0, stream,
                           x, Wt, P, M, S);
        hipLaunchKernelGGL(gate_combine, dim3((M + 3) / 4), dim3(256), 0, stream,
                           P, gb, out, wsc, M, S);
        hipLaunchKernelGGL(gate_refine, dim3(256), dim3(256), 0, stream,
                           x, W, gb, out, wsc, M);
    } else {
        const bool refine_ok = ws_size >= (size_t)(1 + MAXFLAG) * sizeof(int);
        int* wsc = refine_ok ? (int*)d_ws : (int*)nullptr;
        if (refine_ok) hipMemsetAsync(d_ws, 0, sizeof(int), stream);
        hipLaunchKernelGGL(gate_mono, dim3(M / BM), dim3(256), 0, stream,
                           x, W, gb, out, wsc, M);
        if (refine_ok)
            hipLaunchKernelGGL(gate_refine, dim3(256), dim3(256), 0, stream,
                               x, W, gb, out, wsc, M);
    }
}